// Round 1
// baseline (1415.620 us; speedup 1.0000x reference)
//
#include <hip/hip_runtime.h>

#define N_NODES 100000
#define N_EDGES 3200000
#define NF 256
#define HID 64

// ---------- degree accumulation (dst-side, weights) ----------
__global__ void deg_kernel(const int* __restrict__ ei, const float* __restrict__ ew,
                           float* __restrict__ deg) {
    int e = blockIdx.x * blockDim.x + threadIdx.x;
    if (e < N_EDGES) {
        int d = ei[N_EDGES + e];
        atomicAdd(&deg[d], ew[e]);
    }
}

// dinv = rsqrt(deg + 1)  (self-loop adds 1; deg+1 > 0 always)
__global__ void dinv_kernel(float* __restrict__ deg) {
    int i = blockIdx.x * blockDim.x + threadIdx.x;
    if (i < N_NODES) {
        deg[i] = rsqrtf(deg[i] + 1.0f);
    }
}

// norm[e] = dinv[src] * ew[e] * dinv[dst]
__global__ void norm_kernel(const int* __restrict__ ei, const float* __restrict__ ew,
                            const float* __restrict__ dinv, float* __restrict__ nrm) {
    int e = blockIdx.x * blockDim.x + threadIdx.x;
    if (e < N_EDGES) {
        int s = ei[e];
        int d = ei[N_EDGES + e];
        nrm[e] = dinv[s] * ew[e] * dinv[d];
    }
}

// ---------- h = x @ W1  ([N,256] @ [256,64]) ----------
// Block: 256 threads = 16 col-groups (4 cols each) x 16 row-groups (4 rows each)
// W1 in LDS (64 KB); x streamed from global via float4 (broadcast within row-group).
__launch_bounds__(256)
__global__ void gemm1_kernel(const float* __restrict__ x, const float* __restrict__ W,
                             float* __restrict__ h) {
    __shared__ float Ws[NF * HID];  // 64 KB
    int t = threadIdx.x;
    for (int i = t; i < NF * HID; i += 256) Ws[i] = W[i];
    __syncthreads();

    int tc = t & 15;        // col group: cols 4*tc .. 4*tc+3
    int tr = t >> 4;        // row group: rows row0 .. row0+3
    int row0 = blockIdx.x * 64 + tr * 4;

    float acc[4][4] = {};
    for (int k = 0; k < NF; k += 4) {
        float4 wv[4];
#pragma unroll
        for (int kk = 0; kk < 4; ++kk)
            wv[kk] = *(const float4*)&Ws[(k + kk) * HID + 4 * tc];
#pragma unroll
        for (int r = 0; r < 4; ++r) {
            int row = row0 + r;
            if (row < N_NODES) {
                float4 xv = *(const float4*)&x[(size_t)row * NF + k];
#pragma unroll
                for (int c = 0; c < 4; ++c) {
                    acc[r][c] = fmaf(xv.x, ((const float*)&wv[0])[c], acc[r][c]);
                    acc[r][c] = fmaf(xv.y, ((const float*)&wv[1])[c], acc[r][c]);
                    acc[r][c] = fmaf(xv.z, ((const float*)&wv[2])[c], acc[r][c]);
                    acc[r][c] = fmaf(xv.w, ((const float*)&wv[3])[c], acc[r][c]);
                }
            }
        }
    }
#pragma unroll
    for (int r = 0; r < 4; ++r) {
        int row = row0 + r;
        if (row < N_NODES) {
            float4 o = make_float4(acc[r][0], acc[r][1], acc[r][2], acc[r][3]);
            *(float4*)&h[(size_t)row * HID + 4 * tc] = o;
        }
    }
}

// ---------- layer-1 aggregation: one wave per edge, lane = feature ----------
__global__ void agg1_kernel(const int* __restrict__ ei, const float* __restrict__ nrm,
                            const float* __restrict__ h, float* __restrict__ agg) {
    int lane = threadIdx.x & 63;
    int gw = (blockIdx.x * blockDim.x + threadIdx.x) >> 6;
    int nw = (gridDim.x * blockDim.x) >> 6;
    for (int e = gw; e < N_EDGES; e += nw) {
        int s = ei[e];
        int d = ei[N_EDGES + e];
        float w = nrm[e];
        float v = w * h[(size_t)s * HID + lane];
        atomicAdd(&agg[(size_t)d * HID + lane], v);
    }
}

// self-loop + bias + ELU, written in-place over h
__global__ void post1_kernel(const float* __restrict__ agg, const float* __restrict__ dinv,
                             const float* __restrict__ b1, float* __restrict__ h) {
    int idx = blockIdx.x * blockDim.x + threadIdx.x;
    if (idx < N_NODES * HID) {
        int i = idx >> 6;
        int j = idx & 63;
        float di = dinv[i];
        float v = agg[idx] + di * di * h[idx] + b1[j];
        h[idx] = (v > 0.0f) ? v : (expf(v) - 1.0f);
    }
}

// ---------- z = h2 @ W2  ([N,64] @ [64,1]) : wave per row ----------
__global__ void gemm2_kernel(const float* __restrict__ h2, const float* __restrict__ W2,
                             float* __restrict__ z) {
    int lane = threadIdx.x & 63;
    int row = (blockIdx.x * blockDim.x + threadIdx.x) >> 6;
    if (row < N_NODES) {
        float v = h2[(size_t)row * HID + lane] * W2[lane];
#pragma unroll
        for (int off = 32; off > 0; off >>= 1) v += __shfl_down(v, off);
        if (lane == 0) z[row] = v;
    }
}

// ---------- layer-2 aggregation: thread per edge (scalar) ----------
__global__ void agg2_kernel(const int* __restrict__ ei, const float* __restrict__ nrm,
                            const float* __restrict__ z, float* __restrict__ agg) {
    int e = blockIdx.x * blockDim.x + threadIdx.x;
    if (e < N_EDGES) {
        int s = ei[e];
        int d = ei[N_EDGES + e];
        atomicAdd(&agg[d], nrm[e] * z[s]);
    }
}

// self-loop + bias + sigmoid
__global__ void final_kernel(const float* __restrict__ agg, const float* __restrict__ dinv,
                             const float* __restrict__ z, const float* __restrict__ b2,
                             float* __restrict__ out) {
    int i = blockIdx.x * blockDim.x + threadIdx.x;
    if (i < N_NODES) {
        float di = dinv[i];
        float v = agg[i] + di * di * z[i] + b2[0];
        out[i] = 1.0f / (1.0f + expf(-v));
    }
}

extern "C" void kernel_launch(void* const* d_in, const int* in_sizes, int n_in,
                              void* d_out, int out_size, void* d_ws, size_t ws_size,
                              hipStream_t stream) {
    const float* x  = (const float*)d_in[0];
    const int*   ei = (const int*)d_in[1];
    const float* ew = (const float*)d_in[2];
    const float* W1 = (const float*)d_in[3];
    const float* b1 = (const float*)d_in[4];
    const float* W2 = (const float*)d_in[5];
    const float* b2 = (const float*)d_in[6];
    float* out = (float*)d_out;

    float* ws   = (float*)d_ws;
    float* dinv = ws;                                   // N
    float* nrm  = dinv + N_NODES;                       // E
    float* h    = nrm + N_EDGES;                        // N*HID
    float* agg1 = h + (size_t)N_NODES * HID;            // N*HID
    float* z    = agg1 + (size_t)N_NODES * HID;         // N
    float* agg2 = z + N_NODES;                          // N

    hipMemsetAsync(dinv, 0, N_NODES * sizeof(float), stream);
    hipMemsetAsync(agg1, 0, (size_t)N_NODES * HID * sizeof(float), stream);
    hipMemsetAsync(agg2, 0, N_NODES * sizeof(float), stream);

    deg_kernel<<<(N_EDGES + 255) / 256, 256, 0, stream>>>(ei, ew, dinv);
    dinv_kernel<<<(N_NODES + 255) / 256, 256, 0, stream>>>(dinv);
    norm_kernel<<<(N_EDGES + 255) / 256, 256, 0, stream>>>(ei, ew, dinv, nrm);

    gemm1_kernel<<<(N_NODES + 63) / 64, 256, 0, stream>>>(x, W1, h);
    agg1_kernel<<<8192, 256, 0, stream>>>(ei, nrm, h, agg1);
    post1_kernel<<<(N_NODES * HID + 255) / 256, 256, 0, stream>>>(agg1, dinv, b1, h);

    gemm2_kernel<<<(N_NODES * 64 + 255) / 256, 256, 0, stream>>>(h, W2, z);
    agg2_kernel<<<(N_EDGES + 255) / 256, 256, 0, stream>>>(ei, nrm, z, agg2);
    final_kernel<<<(N_NODES + 255) / 256, 256, 0, stream>>>(agg2, dinv, z, b2, out);
}

// Round 2
// 1304.441 us; speedup vs baseline: 1.0852x; 1.0852x over previous
//
#include <hip/hip_runtime.h>

#define N_NODES 100000
#define N_EDGES 3200000
#define NF 256
#define HID 64

// ---------- degree (weighted) + edge count per dst ----------
__global__ void degcnt_kernel(const int* __restrict__ ei, const float* __restrict__ ew,
                              float* __restrict__ deg, int* __restrict__ cnt) {
    int e = blockIdx.x * blockDim.x + threadIdx.x;
    if (e < N_EDGES) {
        int d = ei[N_EDGES + e];
        atomicAdd(&deg[d], ew[e]);
        atomicAdd(&cnt[d], 1);
    }
}

// dinv = rsqrt(deg + 1)  (self-loop adds 1; deg+1 > 0 always)
__global__ void dinv_kernel(float* __restrict__ deg) {
    int i = blockIdx.x * blockDim.x + threadIdx.x;
    if (i < N_NODES) deg[i] = rsqrtf(deg[i] + 1.0f);
}

// ---------- exclusive prefix sum over cnt -> row_ptr, cursor (single block) ----------
__launch_bounds__(1024)
__global__ void scan_kernel(const int* __restrict__ cnt, int* __restrict__ row_ptr,
                            int* __restrict__ cursor) {
    __shared__ int part[1024];
    int t = threadIdx.x;
    const int CH = (N_NODES + 1023) / 1024;
    int begin = t * CH;
    int endi = begin + CH; if (endi > N_NODES) endi = N_NODES;
    int s = 0;
    for (int i = begin; i < endi; ++i) s += cnt[i];
    part[t] = s;
    __syncthreads();
    for (int off = 1; off < 1024; off <<= 1) {
        int v = (t >= off) ? part[t - off] : 0;
        __syncthreads();
        part[t] += v;
        __syncthreads();
    }
    int run = (t == 0) ? 0 : part[t - 1];
    for (int i = begin; i < endi; ++i) {
        row_ptr[i] = run;
        cursor[i] = run;
        run += cnt[i];
    }
    if (t == 1023) row_ptr[N_NODES] = part[1023];
}

// ---------- scatter edges into CSR (norm fused) ----------
__global__ void scatter_kernel(const int* __restrict__ ei, const float* __restrict__ ew,
                               const float* __restrict__ dinv, int* __restrict__ cursor,
                               int* __restrict__ srcs, float* __restrict__ wts) {
    int e = blockIdx.x * blockDim.x + threadIdx.x;
    if (e < N_EDGES) {
        int s = ei[e];
        int d = ei[N_EDGES + e];
        int pos = atomicAdd(&cursor[d], 1);
        srcs[pos] = s;
        wts[pos] = dinv[s] * ew[e] * dinv[d];
    }
}

// ---------- h = x @ W1  ([N,256] @ [256,64]) ----------
__launch_bounds__(256)
__global__ void gemm1_kernel(const float* __restrict__ x, const float* __restrict__ W,
                             float* __restrict__ h) {
    __shared__ float Ws[NF * HID];  // 64 KB
    int t = threadIdx.x;
    for (int i = t; i < NF * HID; i += 256) Ws[i] = W[i];
    __syncthreads();

    int tc = t & 15;
    int tr = t >> 4;
    int row0 = blockIdx.x * 64 + tr * 4;

    float acc[4][4] = {};
    for (int k = 0; k < NF; k += 4) {
        float4 wv[4];
#pragma unroll
        for (int kk = 0; kk < 4; ++kk)
            wv[kk] = *(const float4*)&Ws[(k + kk) * HID + 4 * tc];
#pragma unroll
        for (int r = 0; r < 4; ++r) {
            int row = row0 + r;
            if (row < N_NODES) {
                float4 xv = *(const float4*)&x[(size_t)row * NF + k];
#pragma unroll
                for (int c = 0; c < 4; ++c) {
                    acc[r][c] = fmaf(xv.x, ((const float*)&wv[0])[c], acc[r][c]);
                    acc[r][c] = fmaf(xv.y, ((const float*)&wv[1])[c], acc[r][c]);
                    acc[r][c] = fmaf(xv.z, ((const float*)&wv[2])[c], acc[r][c]);
                    acc[r][c] = fmaf(xv.w, ((const float*)&wv[3])[c], acc[r][c]);
                }
            }
        }
    }
#pragma unroll
    for (int r = 0; r < 4; ++r) {
        int row = row0 + r;
        if (row < N_NODES) {
            float4 o = make_float4(acc[r][0], acc[r][1], acc[r][2], acc[r][3]);
            *(float4*)&h[(size_t)row * HID + 4 * tc] = o;
        }
    }
}

// ---------- fused layer-1 aggregation + self-loop + bias + ELU + @W2 ----------
// One wave per dst node; lane = feature.
__launch_bounds__(256)
__global__ void fused1_kernel(const int* __restrict__ row_ptr, const int* __restrict__ srcs,
                              const float* __restrict__ wts, const float* __restrict__ h,
                              const float* __restrict__ dinv, const float* __restrict__ b1,
                              const float* __restrict__ W2, float* __restrict__ z) {
    int lane = threadIdx.x & 63;
    int d = (blockIdx.x * blockDim.x + threadIdx.x) >> 6;
    if (d >= N_NODES) return;

    int start = row_ptr[d];
    int end = row_ptr[d + 1];

    float acc = 0.0f;
    for (int base = start; base < end; base += 64) {
        int n = end - base; if (n > 64) n = 64;
        int idx = base + lane;
        int s_l = (lane < n) ? srcs[idx] : 0;
        float w_l = (lane < n) ? wts[idx] : 0.0f;
        for (int j = 0; j < n; ++j) {
            int s = __shfl(s_l, j);
            float w = __shfl(w_l, j);
            acc = fmaf(w, h[(size_t)s * HID + lane], acc);
        }
    }

    float di = dinv[d];
    float v = acc + di * di * h[(size_t)d * HID + lane] + b1[lane];
    v = (v > 0.0f) ? v : (__expf(v) - 1.0f);

    float p = v * W2[lane];
#pragma unroll
    for (int off = 32; off > 0; off >>= 1) p += __shfl_down(p, off);
    if (lane == 0) z[d] = p;
}

// ---------- fused layer-2 aggregation + self-loop + bias + sigmoid ----------
// One wave per dst node; lanes stride over edges.
__launch_bounds__(256)
__global__ void fused2_kernel(const int* __restrict__ row_ptr, const int* __restrict__ srcs,
                              const float* __restrict__ wts, const float* __restrict__ z,
                              const float* __restrict__ dinv, const float* __restrict__ b2,
                              float* __restrict__ out) {
    int lane = threadIdx.x & 63;
    int d = (blockIdx.x * blockDim.x + threadIdx.x) >> 6;
    if (d >= N_NODES) return;

    int start = row_ptr[d];
    int end = row_ptr[d + 1];

    float acc = 0.0f;
    for (int i = start + lane; i < end; i += 64)
        acc = fmaf(wts[i], z[srcs[i]], acc);
#pragma unroll
    for (int off = 32; off > 0; off >>= 1) acc += __shfl_down(acc, off);

    if (lane == 0) {
        float di = dinv[d];
        float v = acc + di * di * z[d] + b2[0];
        out[d] = 1.0f / (1.0f + __expf(-v));
    }
}

extern "C" void kernel_launch(void* const* d_in, const int* in_sizes, int n_in,
                              void* d_out, int out_size, void* d_ws, size_t ws_size,
                              hipStream_t stream) {
    const float* x  = (const float*)d_in[0];
    const int*   ei = (const int*)d_in[1];
    const float* ew = (const float*)d_in[2];
    const float* W1 = (const float*)d_in[3];
    const float* b1 = (const float*)d_in[4];
    const float* W2 = (const float*)d_in[5];
    const float* b2 = (const float*)d_in[6];
    float* out = (float*)d_out;

    char* ws = (char*)d_ws;
    float* dinv    = (float*)ws;                                ws += (size_t)N_NODES * 4;
    int*   cnt     = (int*)ws;                                  ws += (size_t)N_NODES * 4;
    int*   row_ptr = (int*)ws;                                  ws += (size_t)(N_NODES + 1) * 4;
    int*   cursor  = (int*)ws;                                  ws += (size_t)N_NODES * 4;
    int*   srcs    = (int*)ws;                                  ws += (size_t)N_EDGES * 4;
    float* wts     = (float*)ws;                                ws += (size_t)N_EDGES * 4;
    float* h       = (float*)ws;                                ws += (size_t)N_NODES * HID * 4;
    float* z       = (float*)ws;                                ws += (size_t)N_NODES * 4;

    hipMemsetAsync(dinv, 0, N_NODES * sizeof(float), stream);
    hipMemsetAsync(cnt, 0, N_NODES * sizeof(int), stream);

    degcnt_kernel<<<(N_EDGES + 255) / 256, 256, 0, stream>>>(ei, ew, dinv, cnt);
    dinv_kernel<<<(N_NODES + 255) / 256, 256, 0, stream>>>(dinv);
    scan_kernel<<<1, 1024, 0, stream>>>(cnt, row_ptr, cursor);
    scatter_kernel<<<(N_EDGES + 255) / 256, 256, 0, stream>>>(ei, ew, dinv, cursor, srcs, wts);

    gemm1_kernel<<<(N_NODES + 63) / 64, 256, 0, stream>>>(x, W1, h);

    fused1_kernel<<<(N_NODES * 64 + 255) / 256, 256, 0, stream>>>(row_ptr, srcs, wts, h, dinv,
                                                                  b1, W2, z);
    fused2_kernel<<<(N_NODES * 64 + 255) / 256, 256, 0, stream>>>(row_ptr, srcs, wts, z, dinv,
                                                                  b2, out);
}

// Round 3
// 1090.541 us; speedup vs baseline: 1.2981x; 1.1961x over previous
//
#include <hip/hip_runtime.h>

#define N_NODES 100000
#define N_EDGES 3200000
#define NF 256
#define HID 64

// ---------- packed degree: cnt<<40 | fixed-point(ew sum, scale 2^32) ----------
__global__ void degcnt_kernel(const int* __restrict__ ei, const float* __restrict__ ew,
                              unsigned long long* __restrict__ packed) {
    int e = blockIdx.x * blockDim.x + threadIdx.x;
    if (e < N_EDGES) {
        int d = ei[N_EDGES + e];
        unsigned long long fx = (unsigned long long)(ew[e] * 4294967296.0f);
        atomicAdd(&packed[d], (1ULL << 40) | fx);
    }
}

// dinv = rsqrt(deg + 1); also unpack cnt
__global__ void dinv_kernel(const unsigned long long* __restrict__ packed,
                            float* __restrict__ dinv, int* __restrict__ cnt) {
    int i = blockIdx.x * blockDim.x + threadIdx.x;
    if (i < N_NODES) {
        unsigned long long p = packed[i];
        float deg = (float)(p & ((1ULL << 40) - 1)) * (1.0f / 4294967296.0f);
        cnt[i] = (int)(p >> 40);
        dinv[i] = rsqrtf(deg + 1.0f);
    }
}

// ---------- exclusive prefix sum over cnt -> row_ptr, cursor (single block) ----------
__launch_bounds__(1024)
__global__ void scan_kernel(const int* __restrict__ cnt, int* __restrict__ row_ptr,
                            int* __restrict__ cursor) {
    __shared__ int part[1024];
    int t = threadIdx.x;
    const int CH = (N_NODES + 1023) / 1024;
    int begin = t * CH;
    int endi = begin + CH; if (endi > N_NODES) endi = N_NODES;
    int s = 0;
    for (int i = begin; i < endi; ++i) s += cnt[i];
    part[t] = s;
    __syncthreads();
    for (int off = 1; off < 1024; off <<= 1) {
        int v = (t >= off) ? part[t - off] : 0;
        __syncthreads();
        part[t] += v;
        __syncthreads();
    }
    int run = (t == 0) ? 0 : part[t - 1];
    for (int i = begin; i < endi; ++i) {
        row_ptr[i] = run;
        cursor[i] = run;
        run += cnt[i];
    }
    if (t == 1023) row_ptr[N_NODES] = part[1023];
}

// ---------- scatter edges into CSR: packed (src, weight-bits) 8B writes ----------
__global__ void scatter_kernel(const int* __restrict__ ei, const float* __restrict__ ew,
                               const float* __restrict__ dinv, int* __restrict__ cursor,
                               int2* __restrict__ ebuf) {
    int e = blockIdx.x * blockDim.x + threadIdx.x;
    if (e < N_EDGES) {
        int s = ei[e];
        int d = ei[N_EDGES + e];
        int pos = atomicAdd(&cursor[d], 1);
        float w = dinv[s] * ew[e] * dinv[d];
        ebuf[pos] = make_int2(s, __float_as_int(w));
    }
}

// ---------- h = x @ W1  ([N,256] @ [256,64]) -> bf16 ----------
__device__ __forceinline__ unsigned short f2bf(float v) {
    unsigned int u = __float_as_uint(v);
    u += 0x7FFFu + ((u >> 16) & 1u);
    return (unsigned short)(u >> 16);
}

__launch_bounds__(256)
__global__ void gemm1_kernel(const float* __restrict__ x, const float* __restrict__ W,
                             unsigned short* __restrict__ h) {
    __shared__ float Ws[NF * HID];  // 64 KB
    int t = threadIdx.x;
    for (int i = t; i < NF * HID; i += 256) Ws[i] = W[i];
    __syncthreads();

    int tc = t & 15;
    int tr = t >> 4;
    int row0 = blockIdx.x * 64 + tr * 4;

    float acc[4][4] = {};
    for (int k = 0; k < NF; k += 4) {
        float4 wv[4];
#pragma unroll
        for (int kk = 0; kk < 4; ++kk)
            wv[kk] = *(const float4*)&Ws[(k + kk) * HID + 4 * tc];
#pragma unroll
        for (int r = 0; r < 4; ++r) {
            int row = row0 + r;
            if (row < N_NODES) {
                float4 xv = *(const float4*)&x[(size_t)row * NF + k];
#pragma unroll
                for (int c = 0; c < 4; ++c) {
                    acc[r][c] = fmaf(xv.x, ((const float*)&wv[0])[c], acc[r][c]);
                    acc[r][c] = fmaf(xv.y, ((const float*)&wv[1])[c], acc[r][c]);
                    acc[r][c] = fmaf(xv.z, ((const float*)&wv[2])[c], acc[r][c]);
                    acc[r][c] = fmaf(xv.w, ((const float*)&wv[3])[c], acc[r][c]);
                }
            }
        }
    }
#pragma unroll
    for (int r = 0; r < 4; ++r) {
        int row = row0 + r;
        if (row < N_NODES) {
            ushort4 o;
            o.x = f2bf(acc[r][0]); o.y = f2bf(acc[r][1]);
            o.z = f2bf(acc[r][2]); o.w = f2bf(acc[r][3]);
            *(ushort4*)&h[(size_t)row * HID + 4 * tc] = o;
        }
    }
}

// ---------- fused layer-1 aggregation + self-loop + bias + ELU + @W2 ----------
// One wave per dst node; lane = feature. h is bf16 (128B gather per edge).
__launch_bounds__(256)
__global__ void fused1_kernel(const int* __restrict__ row_ptr, const int2* __restrict__ ebuf,
                              const unsigned short* __restrict__ h,
                              const float* __restrict__ dinv, const float* __restrict__ b1,
                              const float* __restrict__ W2, float* __restrict__ z) {
    int lane = threadIdx.x & 63;
    int d = (blockIdx.x * blockDim.x + threadIdx.x) >> 6;
    if (d >= N_NODES) return;

    int start = row_ptr[d];
    int end = row_ptr[d + 1];

    float acc = 0.0f;
    for (int base = start; base < end; base += 64) {
        int n = end - base; if (n > 64) n = 64;
        int idx = base + lane;
        int2 e = (lane < n) ? ebuf[idx] : make_int2(0, 0);
        for (int j = 0; j < n; ++j) {
            int s = __shfl(e.x, j);
            float w = __int_as_float(__shfl(e.y, j));
            float hv = __uint_as_float((unsigned int)h[(size_t)s * HID + lane] << 16);
            acc = fmaf(w, hv, acc);
        }
    }

    float di = dinv[d];
    float hd = __uint_as_float((unsigned int)h[(size_t)d * HID + lane] << 16);
    float v = acc + di * di * hd + b1[lane];
    v = (v > 0.0f) ? v : (__expf(v) - 1.0f);

    float p = v * W2[lane];
#pragma unroll
    for (int off = 32; off > 0; off >>= 1) p += __shfl_down(p, off);
    if (lane == 0) z[d] = p;
}

// ---------- fused layer-2 aggregation + self-loop + bias + sigmoid ----------
__launch_bounds__(256)
__global__ void fused2_kernel(const int* __restrict__ row_ptr, const int2* __restrict__ ebuf,
                              const float* __restrict__ z, const float* __restrict__ dinv,
                              const float* __restrict__ b2, float* __restrict__ out) {
    int lane = threadIdx.x & 63;
    int d = (blockIdx.x * blockDim.x + threadIdx.x) >> 6;
    if (d >= N_NODES) return;

    int start = row_ptr[d];
    int end = row_ptr[d + 1];

    float acc = 0.0f;
    for (int i = start + lane; i < end; i += 64) {
        int2 e = ebuf[i];
        acc = fmaf(__int_as_float(e.y), z[e.x], acc);
    }
#pragma unroll
    for (int off = 32; off > 0; off >>= 1) acc += __shfl_down(acc, off);

    if (lane == 0) {
        float di = dinv[d];
        float v = acc + di * di * z[d] + b2[0];
        out[d] = 1.0f / (1.0f + __expf(-v));
    }
}

extern "C" void kernel_launch(void* const* d_in, const int* in_sizes, int n_in,
                              void* d_out, int out_size, void* d_ws, size_t ws_size,
                              hipStream_t stream) {
    const float* x  = (const float*)d_in[0];
    const int*   ei = (const int*)d_in[1];
    const float* ew = (const float*)d_in[2];
    const float* W1 = (const float*)d_in[3];
    const float* b1 = (const float*)d_in[4];
    const float* W2 = (const float*)d_in[5];
    const float* b2 = (const float*)d_in[6];
    float* out = (float*)d_out;

    char* ws = (char*)d_ws;
    unsigned long long* packed = (unsigned long long*)ws;       ws += (size_t)N_NODES * 8;
    float* dinv    = (float*)ws;                                ws += (size_t)N_NODES * 4;
    int*   cnt     = (int*)ws;                                  ws += (size_t)N_NODES * 4;
    int*   row_ptr = (int*)ws;                                  ws += (size_t)(N_NODES + 1) * 4;
    int*   cursor  = (int*)ws;                                  ws += (size_t)N_NODES * 4;
    int2*  ebuf    = (int2*)ws;                                 ws += (size_t)N_EDGES * 8;
    unsigned short* h = (unsigned short*)ws;                    ws += (size_t)N_NODES * HID * 2;
    float* z       = (float*)ws;                                ws += (size_t)N_NODES * 4;

    hipMemsetAsync(packed, 0, N_NODES * 8, stream);

    degcnt_kernel<<<(N_EDGES + 255) / 256, 256, 0, stream>>>(ei, ew, packed);
    dinv_kernel<<<(N_NODES + 255) / 256, 256, 0, stream>>>(packed, dinv, cnt);
    scan_kernel<<<1, 1024, 0, stream>>>(cnt, row_ptr, cursor);
    scatter_kernel<<<(N_EDGES + 255) / 256, 256, 0, stream>>>(ei, ew, dinv, cursor, ebuf);

    gemm1_kernel<<<(N_NODES + 63) / 64, 256, 0, stream>>>(x, W1, h);

    fused1_kernel<<<(N_NODES * 64 + 255) / 256, 256, 0, stream>>>(row_ptr, ebuf, h, dinv,
                                                                  b1, W2, z);
    fused2_kernel<<<(N_NODES * 64 + 255) / 256, 256, 0, stream>>>(row_ptr, ebuf, z, dinv,
                                                                  b2, out);
}

// Round 4
// 899.458 us; speedup vs baseline: 1.5739x; 1.2124x over previous
//
#include <hip/hip_runtime.h>

#define N_NODES 100000
#define N_EDGES 3200000
#define NF 256
#define HID 64

typedef short short8 __attribute__((ext_vector_type(8)));
typedef float f32x4 __attribute__((ext_vector_type(4)));

__device__ __forceinline__ unsigned short f2bf(float v) {
    unsigned int u = __float_as_uint(v);
    u += 0x7FFFu + ((u >> 16) & 1u);
    return (unsigned short)(u >> 16);
}

// ---------- packed degree: cnt<<40 | fixed-point(ew sum, scale 2^32) ----------
__global__ void degcnt_kernel(const int* __restrict__ ei, const float* __restrict__ ew,
                              unsigned long long* __restrict__ packed) {
    int e = blockIdx.x * blockDim.x + threadIdx.x;
    if (e < N_EDGES) {
        int d = ei[N_EDGES + e];
        unsigned long long fx = (unsigned long long)(ew[e] * 4294967296.0f);
        atomicAdd(&packed[d], (1ULL << 40) | fx);
    }
}

// dinv = rsqrt(deg + 1); also unpack cnt
__global__ void dinv_kernel(const unsigned long long* __restrict__ packed,
                            float* __restrict__ dinv, int* __restrict__ cnt) {
    int i = blockIdx.x * blockDim.x + threadIdx.x;
    if (i < N_NODES) {
        unsigned long long p = packed[i];
        float deg = (float)(p & ((1ULL << 40) - 1)) * (1.0f / 4294967296.0f);
        cnt[i] = (int)(p >> 40);
        dinv[i] = rsqrtf(deg + 1.0f);
    }
}

// ---------- exclusive prefix sum over cnt -> row_ptr, cursor (single block) ----------
__launch_bounds__(1024)
__global__ void scan_kernel(const int* __restrict__ cnt, int* __restrict__ row_ptr,
                            int* __restrict__ cursor) {
    __shared__ int part[1024];
    int t = threadIdx.x;
    const int CH = (N_NODES + 1023) / 1024;
    int begin = t * CH;
    int endi = begin + CH; if (endi > N_NODES) endi = N_NODES;
    int s = 0;
    for (int i = begin; i < endi; ++i) s += cnt[i];
    part[t] = s;
    __syncthreads();
    for (int off = 1; off < 1024; off <<= 1) {
        int v = (t >= off) ? part[t - off] : 0;
        __syncthreads();
        part[t] += v;
        __syncthreads();
    }
    int run = (t == 0) ? 0 : part[t - 1];
    for (int i = begin; i < endi; ++i) {
        row_ptr[i] = run;
        cursor[i] = run;
        run += cnt[i];
    }
    if (t == 1023) row_ptr[N_NODES] = part[1023];
}

// ---------- scatter edges into CSR: packed (src, weight-bits) 8B writes ----------
__global__ void scatter_kernel(const int* __restrict__ ei, const float* __restrict__ ew,
                               const float* __restrict__ dinv, int* __restrict__ cursor,
                               int2* __restrict__ ebuf) {
    int e = blockIdx.x * blockDim.x + threadIdx.x;
    if (e < N_EDGES) {
        int s = ei[e];
        int d = ei[N_EDGES + e];
        int pos = atomicAdd(&cursor[d], 1);
        float w = dinv[s] * ew[e] * dinv[d];
        ebuf[pos] = make_int2(s, __float_as_int(w));
    }
}

// ---------- one-time W1 swizzle into MFMA B-fragment order (bf16) ----------
// wsw[((kiter*4 + ntile)*64 + lane)*8 + j] = bf16(W[k][n]),
//   k = kiter*32 + (lane>>4)*8 + j, n = ntile*16 + (lane&15)
__global__ void wswiz_kernel(const float* __restrict__ W, unsigned short* __restrict__ wsw) {
    int idx = blockIdx.x * blockDim.x + threadIdx.x;  // 0 .. 16383
    if (idx < NF * HID) {
        int j = idx & 7;
        int lane = (idx >> 3) & 63;
        int ntile = (idx >> 9) & 3;
        int kiter = idx >> 11;
        int k = kiter * 32 + (lane >> 4) * 8 + j;
        int n = ntile * 16 + (lane & 15);
        wsw[idx] = f2bf(W[k * HID + n]);
    }
}

// ---------- h = x @ W1 via MFMA (bf16 in, fp32 acc, bf16 out) ----------
// Block = 4 waves; each wave computes 16 rows x 64 cols. No LDS.
__launch_bounds__(256)
__global__ void gemm1_mfma(const float* __restrict__ x, const unsigned short* __restrict__ wsw,
                           unsigned short* __restrict__ h) {
    int t = threadIdx.x;
    int lane = t & 63;
    int wave = t >> 6;
    int m = lane & 15;        // row within tile
    int quad = lane >> 4;     // k-group selector
    int rowbase = blockIdx.x * 64 + wave * 16;

    int row = rowbase + m;
    if (row >= N_NODES) row = N_NODES - 1;  // clamp (stores guarded)

    const short8* wv = (const short8*)wsw;

    f32x4 acc[4] = {{0.f,0.f,0.f,0.f},{0.f,0.f,0.f,0.f},{0.f,0.f,0.f,0.f},{0.f,0.f,0.f,0.f}};

    const float* xrow = x + (size_t)row * NF;
#pragma unroll
    for (int kiter = 0; kiter < 8; ++kiter) {
        int k0 = kiter * 32 + quad * 8;
        float4 xa = *(const float4*)&xrow[k0];
        float4 xb = *(const float4*)&xrow[k0 + 4];
        short8 a;
        a[0] = (short)f2bf(xa.x); a[1] = (short)f2bf(xa.y);
        a[2] = (short)f2bf(xa.z); a[3] = (short)f2bf(xa.w);
        a[4] = (short)f2bf(xb.x); a[5] = (short)f2bf(xb.y);
        a[6] = (short)f2bf(xb.z); a[7] = (short)f2bf(xb.w);
#pragma unroll
        for (int nt = 0; nt < 4; ++nt) {
            short8 b = wv[(kiter * 4 + nt) * 64 + lane];
            acc[nt] = __builtin_amdgcn_mfma_f32_16x16x32_bf16(a, b, acc[nt], 0, 0, 0);
        }
    }

    // C/D layout: col = lane&15, row = quad*4 + reg
#pragma unroll
    for (int nt = 0; nt < 4; ++nt) {
#pragma unroll
        for (int r = 0; r < 4; ++r) {
            int orow = rowbase + quad * 4 + r;
            if (orow < N_NODES) {
                int ocol = nt * 16 + m;
                h[(size_t)orow * HID + ocol] = f2bf(acc[nt][r]);
            }
        }
    }
}

// ---------- fused layer-1 aggregation + self-loop + bias + ELU + @W2 ----------
// One wave per dst node; lane = feature. h is bf16 (128B gather per edge).
__launch_bounds__(256)
__global__ void fused1_kernel(const int* __restrict__ row_ptr, const int2* __restrict__ ebuf,
                              const unsigned short* __restrict__ h,
                              const float* __restrict__ dinv, const float* __restrict__ b1,
                              const float* __restrict__ W2, float* __restrict__ z) {
    int lane = threadIdx.x & 63;
    int d = (blockIdx.x * blockDim.x + threadIdx.x) >> 6;
    if (d >= N_NODES) return;

    int start = row_ptr[d];
    int end = row_ptr[d + 1];

    float acc = 0.0f;
    for (int base = start; base < end; base += 64) {
        int n = end - base; if (n > 64) n = 64;
        int idx = base + lane;
        int2 e = (lane < n) ? ebuf[idx] : make_int2(0, 0);
        for (int j = 0; j < n; ++j) {
            int s = __shfl(e.x, j);
            float w = __int_as_float(__shfl(e.y, j));
            float hv = __uint_as_float((unsigned int)h[(size_t)s * HID + lane] << 16);
            acc = fmaf(w, hv, acc);
        }
    }

    float di = dinv[d];
    float hd = __uint_as_float((unsigned int)h[(size_t)d * HID + lane] << 16);
    float v = acc + di * di * hd + b1[lane];
    v = (v > 0.0f) ? v : (__expf(v) - 1.0f);

    float p = v * W2[lane];
#pragma unroll
    for (int off = 32; off > 0; off >>= 1) p += __shfl_down(p, off);
    if (lane == 0) z[d] = p;
}

// ---------- fused layer-2 aggregation + self-loop + bias + sigmoid ----------
__launch_bounds__(256)
__global__ void fused2_kernel(const int* __restrict__ row_ptr, const int2* __restrict__ ebuf,
                              const float* __restrict__ z, const float* __restrict__ dinv,
                              const float* __restrict__ b2, float* __restrict__ out) {
    int lane = threadIdx.x & 63;
    int d = (blockIdx.x * blockDim.x + threadIdx.x) >> 6;
    if (d >= N_NODES) return;

    int start = row_ptr[d];
    int end = row_ptr[d + 1];

    float acc = 0.0f;
    for (int i = start + lane; i < end; i += 64) {
        int2 e = ebuf[i];
        acc = fmaf(__int_as_float(e.y), z[e.x], acc);
    }
#pragma unroll
    for (int off = 32; off > 0; off >>= 1) acc += __shfl_down(acc, off);

    if (lane == 0) {
        float di = dinv[d];
        float v = acc + di * di * z[d] + b2[0];
        out[d] = 1.0f / (1.0f + __expf(-v));
    }
}

extern "C" void kernel_launch(void* const* d_in, const int* in_sizes, int n_in,
                              void* d_out, int out_size, void* d_ws, size_t ws_size,
                              hipStream_t stream) {
    const float* x  = (const float*)d_in[0];
    const int*   ei = (const int*)d_in[1];
    const float* ew = (const float*)d_in[2];
    const float* W1 = (const float*)d_in[3];
    const float* b1 = (const float*)d_in[4];
    const float* W2 = (const float*)d_in[5];
    const float* b2 = (const float*)d_in[6];
    float* out = (float*)d_out;

    char* ws = (char*)d_ws;
    unsigned long long* packed = (unsigned long long*)ws;       ws += (size_t)N_NODES * 8;
    float* dinv    = (float*)ws;                                ws += (size_t)N_NODES * 4;
    int*   cnt     = (int*)ws;                                  ws += (size_t)N_NODES * 4;
    int*   row_ptr = (int*)ws;                                  ws += (size_t)(N_NODES + 1) * 4;
    int*   cursor  = (int*)ws;                                  ws += (size_t)N_NODES * 4;
    int2*  ebuf    = (int2*)ws;                                 ws += (size_t)N_EDGES * 8;
    unsigned short* h = (unsigned short*)ws;                    ws += (size_t)N_NODES * HID * 2;
    unsigned short* wsw = (unsigned short*)ws;                  ws += (size_t)NF * HID * 2;
    float* z       = (float*)ws;                                ws += (size_t)N_NODES * 4;

    hipMemsetAsync(packed, 0, N_NODES * 8, stream);

    degcnt_kernel<<<(N_EDGES + 255) / 256, 256, 0, stream>>>(ei, ew, packed);
    dinv_kernel<<<(N_NODES + 255) / 256, 256, 0, stream>>>(packed, dinv, cnt);
    scan_kernel<<<1, 1024, 0, stream>>>(cnt, row_ptr, cursor);
    scatter_kernel<<<(N_EDGES + 255) / 256, 256, 0, stream>>>(ei, ew, dinv, cursor, ebuf);

    wswiz_kernel<<<(NF * HID + 255) / 256, 256, 0, stream>>>(W1, wsw);
    gemm1_mfma<<<(N_NODES + 63) / 64, 256, 0, stream>>>(x, wsw, h);

    fused1_kernel<<<(N_NODES * 64 + 255) / 256, 256, 0, stream>>>(row_ptr, ebuf, h, dinv,
                                                                  b1, W2, z);
    fused2_kernel<<<(N_NODES * 64 + 255) / 256, 256, 0, stream>>>(row_ptr, ebuf, z, dinv,
                                                                  b2, out);
}

// Round 5
// 687.784 us; speedup vs baseline: 2.0582x; 1.3078x over previous
//
#include <hip/hip_runtime.h>

#define N_NODES 100000
#define N_EDGES 3200000
#define NF 256
#define HID 64
#define NBLK ((N_NODES + 255) / 256)   // 391 scan blocks

typedef short short8 __attribute__((ext_vector_type(8)));
typedef float f32x4 __attribute__((ext_vector_type(4)));

__device__ __forceinline__ unsigned short f2bf(float v) {
    unsigned int u = __float_as_uint(v);
    u += 0x7FFFu + ((u >> 16) & 1u);
    return (unsigned short)(u >> 16);
}

// ---------- packed degree: cnt<<40 | fixed-point(ew sum, scale 2^32) ----------
__global__ void degcnt_kernel(const int* __restrict__ ei, const float* __restrict__ ew,
                              unsigned long long* __restrict__ packed) {
    int e = blockIdx.x * blockDim.x + threadIdx.x;
    if (e < N_EDGES) {
        int d = ei[N_EDGES + e];
        unsigned long long fx = (unsigned long long)(ew[e] * 4294967296.0f);
        atomicAdd(&packed[d], (1ULL << 40) | fx);
    }
}

// dinv = rsqrt(deg + 1); unpack cnt; per-block sum of cnt -> bsum
__launch_bounds__(256)
__global__ void dinv_kernel(const unsigned long long* __restrict__ packed,
                            float* __restrict__ dinv, int* __restrict__ cnt,
                            int* __restrict__ bsum) {
    __shared__ int sh[256];
    int t = threadIdx.x;
    int i = blockIdx.x * 256 + t;
    int c = 0;
    if (i < N_NODES) {
        unsigned long long p = packed[i];
        float deg = (float)(p & ((1ULL << 40) - 1)) * (1.0f / 4294967296.0f);
        c = (int)(p >> 40);
        cnt[i] = c;
        dinv[i] = rsqrtf(deg + 1.0f);
    }
    sh[t] = c;
    __syncthreads();
    for (int off = 128; off > 0; off >>= 1) {
        if (t < off) sh[t] += sh[t + off];
        __syncthreads();
    }
    if (t == 0) bsum[blockIdx.x] = sh[0];
}

// ---------- exclusive scan of the 391 block sums (single tiny block) ----------
__launch_bounds__(512)
__global__ void scanb_kernel(int* __restrict__ bsum) {
    __shared__ int sh[512];
    int t = threadIdx.x;
    int v = (t < NBLK) ? bsum[t] : 0;
    sh[t] = v;
    __syncthreads();
    for (int off = 1; off < 512; off <<= 1) {
        int add = (t >= off) ? sh[t - off] : 0;
        __syncthreads();
        sh[t] += add;
        __syncthreads();
    }
    if (t < NBLK) bsum[t] = sh[t] - v;  // exclusive
}

// ---------- block-local scan + offset -> row_ptr, cursor ----------
__launch_bounds__(256)
__global__ void scan2_kernel(const int* __restrict__ cnt, const int* __restrict__ bsum,
                             int* __restrict__ row_ptr, int* __restrict__ cursor) {
    __shared__ int sh[256];
    int t = threadIdx.x;
    int i = blockIdx.x * 256 + t;
    int v = (i < N_NODES) ? cnt[i] : 0;
    sh[t] = v;
    __syncthreads();
    for (int off = 1; off < 256; off <<= 1) {
        int add = (t >= off) ? sh[t - off] : 0;
        __syncthreads();
        sh[t] += add;
        __syncthreads();
    }
    if (i < N_NODES) {
        int excl = bsum[blockIdx.x] + sh[t] - v;
        row_ptr[i] = excl;
        cursor[i] = excl;
    }
    if (i == N_NODES - 1) row_ptr[N_NODES] = N_EDGES;
}

// ---------- scatter edges into CSR: packed (src, weight-bits) 8B writes ----------
__global__ void scatter_kernel(const int* __restrict__ ei, const float* __restrict__ ew,
                               const float* __restrict__ dinv, int* __restrict__ cursor,
                               int2* __restrict__ ebuf) {
    int e = blockIdx.x * blockDim.x + threadIdx.x;
    if (e < N_EDGES) {
        int s = ei[e];
        int d = ei[N_EDGES + e];
        int pos = atomicAdd(&cursor[d], 1);
        float w = dinv[s] * ew[e] * dinv[d];
        ebuf[pos] = make_int2(s, __float_as_int(w));
    }
}

// ---------- one-time W1 swizzle into MFMA B-fragment order (bf16) ----------
__global__ void wswiz_kernel(const float* __restrict__ W, unsigned short* __restrict__ wsw) {
    int idx = blockIdx.x * blockDim.x + threadIdx.x;  // 0 .. 16383
    if (idx < NF * HID) {
        int j = idx & 7;
        int lane = (idx >> 3) & 63;
        int ntile = (idx >> 9) & 3;
        int kiter = idx >> 11;
        int k = kiter * 32 + (lane >> 4) * 8 + j;
        int n = ntile * 16 + (lane & 15);
        wsw[idx] = f2bf(W[k * HID + n]);
    }
}

// ---------- h = x @ W1 via MFMA (bf16 in, fp32 acc, bf16 out) ----------
__launch_bounds__(256)
__global__ void gemm1_mfma(const float* __restrict__ x, const unsigned short* __restrict__ wsw,
                           unsigned short* __restrict__ h) {
    int t = threadIdx.x;
    int lane = t & 63;
    int wave = t >> 6;
    int m = lane & 15;
    int quad = lane >> 4;
    int rowbase = blockIdx.x * 64 + wave * 16;

    int row = rowbase + m;
    if (row >= N_NODES) row = N_NODES - 1;

    const short8* wv = (const short8*)wsw;

    f32x4 acc[4] = {{0.f,0.f,0.f,0.f},{0.f,0.f,0.f,0.f},{0.f,0.f,0.f,0.f},{0.f,0.f,0.f,0.f}};

    const float* xrow = x + (size_t)row * NF;
#pragma unroll
    for (int kiter = 0; kiter < 8; ++kiter) {
        int k0 = kiter * 32 + quad * 8;
        float4 xa = *(const float4*)&xrow[k0];
        float4 xb = *(const float4*)&xrow[k0 + 4];
        short8 a;
        a[0] = (short)f2bf(xa.x); a[1] = (short)f2bf(xa.y);
        a[2] = (short)f2bf(xa.z); a[3] = (short)f2bf(xa.w);
        a[4] = (short)f2bf(xb.x); a[5] = (short)f2bf(xb.y);
        a[6] = (short)f2bf(xb.z); a[7] = (short)f2bf(xb.w);
#pragma unroll
        for (int nt = 0; nt < 4; ++nt) {
            short8 b = wv[(kiter * 4 + nt) * 64 + lane];
            acc[nt] = __builtin_amdgcn_mfma_f32_16x16x32_bf16(a, b, acc[nt], 0, 0, 0);
        }
    }

#pragma unroll
    for (int nt = 0; nt < 4; ++nt) {
#pragma unroll
        for (int r = 0; r < 4; ++r) {
            int orow = rowbase + quad * 4 + r;
            if (orow < N_NODES) {
                int ocol = nt * 16 + m;
                h[(size_t)orow * HID + ocol] = f2bf(acc[nt][r]);
            }
        }
    }
}

// ---------- fused layer-1 aggregation + self-loop + bias + ELU + @W2 ----------
__launch_bounds__(256)
__global__ void fused1_kernel(const int* __restrict__ row_ptr, const int2* __restrict__ ebuf,
                              const unsigned short* __restrict__ h,
                              const float* __restrict__ dinv, const float* __restrict__ b1,
                              const float* __restrict__ W2, float* __restrict__ z) {
    int lane = threadIdx.x & 63;
    int d = (blockIdx.x * blockDim.x + threadIdx.x) >> 6;
    if (d >= N_NODES) return;

    int start = row_ptr[d];
    int end = row_ptr[d + 1];

    float acc = 0.0f;
    for (int base = start; base < end; base += 64) {
        int n = end - base; if (n > 64) n = 64;
        int idx = base + lane;
        int2 e = (lane < n) ? ebuf[idx] : make_int2(0, 0);
        for (int j = 0; j < n; ++j) {
            int s = __shfl(e.x, j);
            float w = __int_as_float(__shfl(e.y, j));
            float hv = __uint_as_float((unsigned int)h[(size_t)s * HID + lane] << 16);
            acc = fmaf(w, hv, acc);
        }
    }

    float di = dinv[d];
    float hd = __uint_as_float((unsigned int)h[(size_t)d * HID + lane] << 16);
    float v = acc + di * di * hd + b1[lane];
    v = (v > 0.0f) ? v : (__expf(v) - 1.0f);

    float p = v * W2[lane];
#pragma unroll
    for (int off = 32; off > 0; off >>= 1) p += __shfl_down(p, off);
    if (lane == 0) z[d] = p;
}

// ---------- fused layer-2 aggregation + self-loop + bias + sigmoid ----------
__launch_bounds__(256)
__global__ void fused2_kernel(const int* __restrict__ row_ptr, const int2* __restrict__ ebuf,
                              const float* __restrict__ z, const float* __restrict__ dinv,
                              const float* __restrict__ b2, float* __restrict__ out) {
    int lane = threadIdx.x & 63;
    int d = (blockIdx.x * blockDim.x + threadIdx.x) >> 6;
    if (d >= N_NODES) return;

    int start = row_ptr[d];
    int end = row_ptr[d + 1];

    float acc = 0.0f;
    for (int i = start + lane; i < end; i += 64) {
        int2 e = ebuf[i];
        acc = fmaf(__int_as_float(e.y), z[e.x], acc);
    }
#pragma unroll
    for (int off = 32; off > 0; off >>= 1) acc += __shfl_down(acc, off);

    if (lane == 0) {
        float di = dinv[d];
        float v = acc + di * di * z[d] + b2[0];
        out[d] = 1.0f / (1.0f + __expf(-v));
    }
}

extern "C" void kernel_launch(void* const* d_in, const int* in_sizes, int n_in,
                              void* d_out, int out_size, void* d_ws, size_t ws_size,
                              hipStream_t stream) {
    const float* x  = (const float*)d_in[0];
    const int*   ei = (const int*)d_in[1];
    const float* ew = (const float*)d_in[2];
    const float* W1 = (const float*)d_in[3];
    const float* b1 = (const float*)d_in[4];
    const float* W2 = (const float*)d_in[5];
    const float* b2 = (const float*)d_in[6];
    float* out = (float*)d_out;

    char* ws = (char*)d_ws;
    unsigned long long* packed = (unsigned long long*)ws;       ws += (size_t)N_NODES * 8;
    float* dinv    = (float*)ws;                                ws += (size_t)N_NODES * 4;
    int*   cnt     = (int*)ws;                                  ws += (size_t)N_NODES * 4;
    int*   row_ptr = (int*)ws;                                  ws += (size_t)(N_NODES + 1) * 4;
    int*   cursor  = (int*)ws;                                  ws += (size_t)N_NODES * 4;
    int*   bsum    = (int*)ws;                                  ws += (size_t)NBLK * 4;
    int2*  ebuf    = (int2*)ws;                                 ws += (size_t)N_EDGES * 8;
    unsigned short* h = (unsigned short*)ws;                    ws += (size_t)N_NODES * HID * 2;
    unsigned short* wsw = (unsigned short*)ws;                  ws += (size_t)NF * HID * 2;
    float* z       = (float*)ws;                                ws += (size_t)N_NODES * 4;

    hipMemsetAsync(packed, 0, N_NODES * 8, stream);

    degcnt_kernel<<<(N_EDGES + 255) / 256, 256, 0, stream>>>(ei, ew, packed);
    dinv_kernel<<<NBLK, 256, 0, stream>>>(packed, dinv, cnt, bsum);
    scanb_kernel<<<1, 512, 0, stream>>>(bsum);
    scan2_kernel<<<NBLK, 256, 0, stream>>>(cnt, bsum, row_ptr, cursor);
    scatter_kernel<<<(N_EDGES + 255) / 256, 256, 0, stream>>>(ei, ew, dinv, cursor, ebuf);

    wswiz_kernel<<<(NF * HID + 255) / 256, 256, 0, stream>>>(W1, wsw);
    gemm1_mfma<<<(N_NODES + 63) / 64, 256, 0, stream>>>(x, wsw, h);

    fused1_kernel<<<(N_NODES * 64 + 255) / 256, 256, 0, stream>>>(row_ptr, ebuf, h, dinv,
                                                                  b1, W2, z);
    fused2_kernel<<<(N_NODES * 64 + 255) / 256, 256, 0, stream>>>(row_ptr, ebuf, z, dinv,
                                                                  b2, out);
}